// Round 3
// baseline (310.672 us; speedup 1.0000x reference)
//
#include <hip/hip_runtime.h>
#include <hip/hip_bf16.h>
#include <stdint.h>

#define N_DIM 2048
#define BATCH_SZ 8192

typedef __bf16 bf16;
typedef __bf16 bf16x4 __attribute__((ext_vector_type(4)));
typedef __bf16 bf16x8 __attribute__((ext_vector_type(8)));
typedef float f32x4 __attribute__((ext_vector_type(4)));

// Async global->LDS, 16B per lane. LDS dest is wave-uniform base + lane*16.
__device__ __forceinline__ void gld16(const bf16* g, bf16* l) {
  __builtin_amdgcn_global_load_lds(
      (const __attribute__((address_space(1))) void*)g,
      (__attribute__((address_space(3))) void*)l, 16, 0, 0);
}

// Build Wb = bf16(W) where W = -S (so exp(W) = Q^T), Wtb = bf16(W^T) = bf16(S).
__global__ void unfold_kernel(const float* __restrict__ Sflat,
                              bf16* __restrict__ Wb,
                              bf16* __restrict__ Wtb) {
  int idx = blockIdx.x * blockDim.x + threadIdx.x;
  int i = idx >> 11;            // row
  int j = idx & (N_DIM - 1);    // col
  float v = 0.0f;               // v = S[i][j]
  if (i < j) {
    int fi = i * (N_DIM - 1) - ((i * (i - 1)) >> 1) + (j - i - 1);
    v = Sflat[fi];
  } else if (i > j) {
    int fi = j * (N_DIM - 1) - ((j * (j - 1)) >> 1) + (i - j - 1);
    v = -Sflat[fi];
  }
  Wb[idx]  = (bf16)(-v);   // W = -S
  Wtb[idx] = (bf16)(v);    // W^T = S
}

// fp32 -> bf16 elementwise (vectorized x4)
__global__ void cast_kernel(const float* __restrict__ in, bf16* __restrict__ out) {
  int t = blockIdx.x * blockDim.x + threadIdx.x;
  float4 v = ((const float4*)in)[t];
  bf16x4 o;
  o.x = (bf16)v.x; o.y = (bf16)v.y; o.z = (bf16)v.z; o.w = (bf16)v.w;
  ((bf16x4*)out)[t] = o;
}

// ---------------------------------------------------------------------------
// Unified pipelined GEMM: C(MxN) = A(MxK) @ Bt(NxK)^T, bf16 in, fp32 acc.
//
// 128x128 tile, 256 threads = 4 waves (2M x 2N), per-wave 64x64 output.
// Ring-3 LDS (48 KB) -> 3 blocks/CU resident; each block contributes ONE
// wave per SIMD, so the 3 waves on a SIMD belong to DIFFERENT blocks and
// are never stalled by the same barrier (TLP overlap, m114 mechanism).
// Staging: prefetch 2 tiles ahead via global_load_lds, counted vmcnt(4) at
// tile boundaries (never drains to 0 in steady state).
// XOR-swizzled LDS layout (verified conflict-free in prior rounds).
//
// MODE 0: Cf[idx] = acc                                   (final out = X@Q)
// MODE 1: O1 = bf16(acc) [W2];  O2 = bf16(I/2 - W/6 + acc/24) [B^T operand]
// MODE 2: O1 = bf16(acc + I + W)                          (Q^T)
// Requires: N % 128 == 0 with gridDim.x == N/128 == 16, K % 32 == 0, K/32 >= 2.
template <int MODE>
__global__ __launch_bounds__(256, 3) void gemm_p(
    const bf16* __restrict__ A, const bf16* __restrict__ Bt,
    float* __restrict__ Cf, bf16* __restrict__ O1, bf16* __restrict__ O2,
    const bf16* __restrict__ Wb, int M, int N, int K) {
  __shared__ __align__(16) bf16 As[3 * 128 * 32];   // 24 KB (ring of 3)
  __shared__ __align__(16) bf16 Bs[3 * 128 * 32];   // 24 KB

  const int tid  = threadIdx.x;
  const int lane = tid & 63;
  const int wave = tid >> 6;     // 0..3
  const int wr   = wave >> 1;    // 0..1  M-half (64 rows)
  const int wc   = wave & 1;     // 0..1  N-half (64 cols)
  const int quad = lane >> 4;
  const int l16  = lane & 15;

  // Bijective XCD swizzle (nwg divisible by 8 in all three uses).
  const int nwg    = gridDim.x * gridDim.y;
  const int linear = blockIdx.y * gridDim.x + blockIdx.x;
  const int wg = (linear & 7) * (nwg >> 3) + (linear >> 3);
  const int bx = wg & 15;        // gridDim.x == 16 (N == 2048)
  const int by = wg >> 4;
  const int m0 = by * 128;
  const int n0 = bx * 128;

  // Staging: each wave stages two 16-row chunks of A (rows 16w, 16w+64) and
  // two of B. Lane l -> row l>>2 within chunk, source slot (l&3)^((l>>3)&3)
  // so LDS[row][s] = G[row][s ^ ((row>>1)&3)]  (conflict-free reads,
  // verified SQ_LDS_BANK_CONFLICT = 0 in rounds 0-2).
  const int srow  = lane >> 2;
  const int sslot = (lane & 3) ^ ((lane >> 3) & 3);
  const bf16* gA1 = A  + (size_t)(m0 + wave * 16 + srow) * K + sslot * 8;
  const bf16* gA2 = gA1 + (size_t)64 * K;
  const bf16* gB1 = Bt + (size_t)(n0 + wave * 16 + srow) * K + sslot * 8;
  const bf16* gB2 = gB1 + (size_t)64 * K;
  bf16* lA1 = As + wave * 512;          // + buf*4096
  bf16* lA2 = As + wave * 512 + 2048;
  bf16* lB1 = Bs + wave * 512;
  bf16* lB2 = Bs + wave * 512 + 2048;

  const int NT = K >> 5;   // K-tiles of 32

  // Prologue: stage tiles 0,1 into ring buffers 0,1 (8 loads/thread), then
  // wait for tile 0 only (tile 1's 4 loads stay in flight).
#pragma unroll
  for (int tt = 0; tt < 2; ++tt) {
    gld16(gA1 + tt * 32, lA1 + tt * 4096);
    gld16(gA2 + tt * 32, lA2 + tt * 4096);
    gld16(gB1 + tt * 32, lB1 + tt * 4096);
    gld16(gB2 + tt * 32, lB2 + tt * 4096);
  }
  asm volatile("s_waitcnt vmcnt(4)" ::: "memory");
  __builtin_amdgcn_sched_barrier(0);
  __builtin_amdgcn_s_barrier();
  __builtin_amdgcn_sched_barrier(0);

  f32x4 acc[4][4] = {};
  const int rswz = (quad ^ ((l16 >> 1) & 3)) * 8;  // reader swizzle (elems)
  const int arow = wr * 64 + l16;
  const int brow = wc * 64 + l16;

  auto body = [&](int t, int u) {
    // Issue staging for tile t+2 into buffer (u+2)%3. That buffer held tile
    // t-1, whose last reads completed before the boundary barrier ending
    // tile t-1 (all waves vmcnt'd their own loads, then barrier published).
    const int b = (u + 2) % 3;
    if (t + 2 < NT) {
      const size_t ko = (size_t)(t + 2) * 32;
      gld16(gA1 + ko, lA1 + b * 4096);
      gld16(gA2 + ko, lA2 + b * 4096);
      gld16(gB1 + ko, lB1 + b * 4096);
      gld16(gB2 + ko, lB2 + b * 4096);
    }
    const bf16* ab = As + u * 4096;
    const bf16* bb = Bs + u * 4096;
    bf16x8 af[4], bfr[4];
#pragma unroll
    for (int mi = 0; mi < 4; ++mi)
      af[mi] = *(const bf16x8*)&ab[(arow + mi * 16) * 32 + rswz];
#pragma unroll
    for (int ni = 0; ni < 4; ++ni)
      bfr[ni] = *(const bf16x8*)&bb[(brow + ni * 16) * 32 + rswz];
    __builtin_amdgcn_s_setprio(1);
#pragma unroll
    for (int mi = 0; mi < 4; ++mi)
#pragma unroll
      for (int ni = 0; ni < 4; ++ni)
        acc[mi][ni] = __builtin_amdgcn_mfma_f32_16x16x32_bf16(
            af[mi], bfr[ni], acc[mi][ni], 0, 0, 0);
    __builtin_amdgcn_s_setprio(0);
    // Boundary: retire tile t+1's 4 loads (issued one tile ago); tile t+2's
    // 4 loads stay in flight. Barrier publishes all waves' LDS writes.
    if (t < NT - 1) {
      if (t + 2 < NT)
        asm volatile("s_waitcnt vmcnt(4)" ::: "memory");
      else
        asm volatile("s_waitcnt vmcnt(0)" ::: "memory");
      __builtin_amdgcn_sched_barrier(0);
      __builtin_amdgcn_s_barrier();
      __builtin_amdgcn_sched_barrier(0);
    }
  };

  const int NT3 = NT - (NT % 3);
#pragma unroll 1
  for (int t0 = 0; t0 < NT3; t0 += 3) {
    body(t0, 0);
    body(t0 + 1, 1);
    body(t0 + 2, 2);
  }
#pragma unroll
  for (int u = 0; u < 3; ++u) {
    const int t = NT3 + u;
    if (t < NT) body(t, u);
  }

  // Epilogue. C/D layout: col = lane&15, row = quad*4 + reg.
#pragma unroll
  for (int mi = 0; mi < 4; ++mi) {
    const int r0 = m0 + wr * 64 + mi * 16 + quad * 4;
#pragma unroll
    for (int ni = 0; ni < 4; ++ni) {
      const int col = n0 + wc * 64 + ni * 16 + l16;
#pragma unroll
      for (int r = 0; r < 4; ++r) {
        const int row = r0 + r;
        const size_t idx = (size_t)row * N + col;
        const float v = acc[mi][ni][r];
        if (MODE == 0) {
          Cf[idx] = v;
        } else if (MODE == 1) {
          // v = W2[row][col]. B = I/2 + W/6 + W2/24 ->
          // B^T = I/2 - W/6 + W2/24  (W antisymmetric, W2 symmetric).
          O1[idx] = (bf16)v;
          const float w = (float)Wb[idx];
          const float d = (row == col) ? 1.0f : 0.0f;
          O2[idx] = (bf16)(0.5f * d - (1.0f / 6.0f) * w + (1.0f / 24.0f) * v);
        } else {  // MODE 2: Q^T = acc + I + W
          const float w = (float)Wb[idx];
          const float d = (row == col) ? 1.0f : 0.0f;
          O1[idx] = (bf16)(v + d + w);
        }
      }
    }
  }
}

extern "C" void kernel_launch(void* const* d_in, const int* in_sizes, int n_in,
                              void* d_out, int out_size, void* d_ws, size_t ws_size,
                              hipStream_t stream) {
  const float* X     = (const float*)d_in[0];
  const float* Sflat = (const float*)d_in[1];
  float* out = (float*)d_out;
  char* ws = (char*)d_ws;

  // Workspace (72 MB total):
  bf16* Xb   = (bf16*)(ws);                 // 32 MB  bf16(X)
  bf16* Wb   = (bf16*)(ws + (32u << 20));   //  8 MB  bf16(W),   W = -S
  bf16* Wtb  = (bf16*)(ws + (40u << 20));   //  8 MB  bf16(W^T)
  bf16* W2b  = (bf16*)(ws + (48u << 20));   //  8 MB  bf16(W^2)
  bf16* Btm  = (bf16*)(ws + (56u << 20));   //  8 MB  bf16(B^T) operand for G2
  bf16* Qtb  = (bf16*)(ws + (64u << 20));   //  8 MB  bf16(Q^T)

  unfold_kernel<<<(N_DIM * N_DIM) / 256, 256, 0, stream>>>(Sflat, Wb, Wtb);
  cast_kernel<<<(BATCH_SZ * N_DIM / 4) / 256, 256, 0, stream>>>(X, Xb);

  // Weight GEMMs: 128x128 tiles -> 256 blocks (1 block/CU).
  const dim3 gW(N_DIM / 128, N_DIM / 128);
  // G1: W2 = W @ W;  epilogue also emits B^T = I/2 - W/6 + W2/24.
  gemm_p<1><<<gW, 256, 0, stream>>>(Wb, Wtb, nullptr, W2b, Btm,
                                    Wb, N_DIM, N_DIM, N_DIM);
  // G2: Q^T = I + W + W2 @ B   (Bt operand = B^T).
  gemm_p<2><<<gW, 256, 0, stream>>>(W2b, Btm, nullptr, Qtb, nullptr,
                                    Wb, N_DIM, N_DIM, N_DIM);
  // G3: out = X @ Q  (Bt = Q^T row-major). 1024 blocks -> 3 resident/CU,
  // 3 independent waves per SIMD.
  gemm_p<0><<<dim3(N_DIM / 128, BATCH_SZ / 128), 256, 0, stream>>>(
      Xb, Qtb, out, nullptr, nullptr, nullptr,
      BATCH_SZ, N_DIM, N_DIM);
}

// Round 4
// 263.096 us; speedup vs baseline: 1.1808x; 1.1808x over previous
//
#include <hip/hip_runtime.h>
#include <hip/hip_bf16.h>
#include <stdint.h>

#define N_DIM 2048
#define BATCH_SZ 8192

typedef __bf16 bf16;
typedef __bf16 bf16x4 __attribute__((ext_vector_type(4)));
typedef __bf16 bf16x8 __attribute__((ext_vector_type(8)));
typedef float f32x4 __attribute__((ext_vector_type(4)));

// Async global->LDS, 16B per lane. LDS dest is wave-uniform base + lane*16.
__device__ __forceinline__ void gld16(const bf16* g, bf16* l) {
  __builtin_amdgcn_global_load_lds(
      (const __attribute__((address_space(1))) void*)g,
      (__attribute__((address_space(3))) void*)l, 16, 0, 0);
}

// Build Wb = bf16(W) where W = -S (so exp(W) = Q^T), Wtb = bf16(W^T) = bf16(S).
__global__ void unfold_kernel(const float* __restrict__ Sflat,
                              bf16* __restrict__ Wb,
                              bf16* __restrict__ Wtb) {
  int idx = blockIdx.x * blockDim.x + threadIdx.x;
  int i = idx >> 11;            // row
  int j = idx & (N_DIM - 1);    // col
  float v = 0.0f;               // v = S[i][j]
  if (i < j) {
    int fi = i * (N_DIM - 1) - ((i * (i - 1)) >> 1) + (j - i - 1);
    v = Sflat[fi];
  } else if (i > j) {
    int fi = j * (N_DIM - 1) - ((j * (j - 1)) >> 1) + (i - j - 1);
    v = -Sflat[fi];
  }
  Wb[idx]  = (bf16)(-v);   // W = -S
  Wtb[idx] = (bf16)(v);    // W^T = S
}

// fp32 -> bf16 elementwise (vectorized x4)
__global__ void cast_kernel(const float* __restrict__ in, bf16* __restrict__ out) {
  int t = blockIdx.x * blockDim.x + threadIdx.x;
  float4 v = ((const float4*)in)[t];
  bf16x4 o;
  o.x = (bf16)v.x; o.y = (bf16)v.y; o.z = (bf16)v.z; o.w = (bf16)v.w;
  ((bf16x4*)out)[t] = o;
}

// ---------------------------------------------------------------------------
// Weight GEMM kernel (G1/G2): C(2048x2048) = A @ Bt^T, bf16 in, fp32 acc.
// 64x128 tile -> 512 blocks = 2 blocks/CU: each SIMD hosts 2 waves from
// DIFFERENT blocks (independent barriers -> m114 TLP overlap), each block
// deep-pipelined: K-step 64 (2 x BK32 sub-buffers), ring-3 (72 KB LDS),
// prefetch-2, counted vmcnt(6) at step boundaries (never drains to 0 in
// steady state). 16 MFMA per wave per barrier period.
// MODE 1: O1 = bf16(acc) [W2];  O2 = bf16(I/2 - W/6 + acc/24) [B^T operand]
// MODE 2: O1 = bf16(acc + I + W)                          (Q^T)
// Requires: M % 64 == 0, N % 128 == 0 (gridDim.x == 16), K % 64 == 0.
template <int MODE>
__global__ __launch_bounds__(256, 2) void gemm_w(
    const bf16* __restrict__ A, const bf16* __restrict__ Bt,
    bf16* __restrict__ O1, bf16* __restrict__ O2,
    const bf16* __restrict__ Wb, int M, int N, int K) {
  // ring slot s in 0..2, k-sub in 0..1:
  __shared__ __align__(16) bf16 As[3 * 2 * 64 * 32];    // 24 KB
  __shared__ __align__(16) bf16 Bs[3 * 2 * 128 * 32];   // 48 KB

  const int tid  = threadIdx.x;
  const int lane = tid & 63;
  const int wave = tid >> 6;     // 0..3
  const int wr   = wave >> 1;    // 0..1  M-half (32 rows)
  const int wc   = wave & 1;     // 0..1  N-half (64 cols)
  const int quad = lane >> 4;
  const int l16  = lane & 15;

  // Bijective XCD swizzle (nwg = 512, divisible by 8).
  const int nwg    = gridDim.x * gridDim.y;
  const int linear = blockIdx.y * gridDim.x + blockIdx.x;
  const int wg = (linear & 7) * (nwg >> 3) + (linear >> 3);
  const int bx = wg & 15;        // gridDim.x == 16
  const int by = wg >> 4;
  const int m0 = by * 64;
  const int n0 = bx * 128;

  // Staging swizzle (verified conflict-free R0-R3):
  // LDS[row][c] = G[row][c ^ ((row>>1)&3)] per 8-elem segment.
  const int srow  = lane >> 2;
  const int sslot = (lane & 3) ^ ((lane >> 3) & 3);
  const bf16* gA  = A  + (size_t)(m0 + wave * 16 + srow) * K + sslot * 8;
  const bf16* gB1 = Bt + (size_t)(n0 + wave * 16 + srow) * K + sslot * 8;
  const bf16* gB2 = gB1 + (size_t)64 * K;
  bf16* lA  = As + wave * 512;   // + (s*2+k)*2048
  bf16* lB1 = Bs + wave * 512;   // + (s*2+k)*4096
  bf16* lB2 = Bs + wave * 512 + 2048;

  const int NS = K >> 6;   // K-steps of 64

  auto STAGE = [&](int t, int s) {
#pragma unroll
    for (int k = 0; k < 2; ++k) {
      const size_t ko = (size_t)t * 64 + k * 32;
      gld16(gA  + ko, lA  + (s * 2 + k) * 2048);
      gld16(gB1 + ko, lB1 + (s * 2 + k) * 4096);
      gld16(gB2 + ko, lB2 + (s * 2 + k) * 4096);
    }
  };

  // Prologue: stage steps 0,1 into slots 0,1 (12 loads/thread), wait for
  // step 0 only (step 1's 6 loads stay in flight).
  STAGE(0, 0);
  STAGE(1, 1);
  asm volatile("s_waitcnt vmcnt(6)" ::: "memory");
  __builtin_amdgcn_sched_barrier(0);
  __builtin_amdgcn_s_barrier();
  __builtin_amdgcn_sched_barrier(0);

  f32x4 acc[2][4] = {};
  const int rswz = (quad ^ ((l16 >> 1) & 3)) * 8;
  const int arow = wr * 32 + l16;
  const int brow = wc * 64 + l16;

  auto body = [&](int t, int s) {
    if (t + 2 < NS) STAGE(t + 2, (s + 2) % 3);
    bf16x8 af[2][2], bfr[2][4];
#pragma unroll
    for (int k = 0; k < 2; ++k) {
      const bf16* ab = As + (s * 2 + k) * 2048;
      const bf16* bb = Bs + (s * 2 + k) * 4096;
#pragma unroll
      for (int mi = 0; mi < 2; ++mi)
        af[k][mi] = *(const bf16x8*)&ab[(arow + mi * 16) * 32 + rswz];
#pragma unroll
      for (int ni = 0; ni < 4; ++ni)
        bfr[k][ni] = *(const bf16x8*)&bb[(brow + ni * 16) * 32 + rswz];
    }
    __builtin_amdgcn_s_setprio(1);
#pragma unroll
    for (int k = 0; k < 2; ++k)
#pragma unroll
      for (int mi = 0; mi < 2; ++mi)
#pragma unroll
        for (int ni = 0; ni < 4; ++ni)
          acc[mi][ni] = __builtin_amdgcn_mfma_f32_16x16x32_bf16(
              af[k][mi], bfr[k][ni], acc[mi][ni], 0, 0, 0);
    __builtin_amdgcn_s_setprio(0);
    // Boundary: retire step t+1's 6 loads; keep step t+2's 6 in flight.
    if (t < NS - 1) {
      if (t + 2 < NS)
        asm volatile("s_waitcnt vmcnt(6)" ::: "memory");
      else
        asm volatile("s_waitcnt vmcnt(0)" ::: "memory");
      __builtin_amdgcn_sched_barrier(0);
      __builtin_amdgcn_s_barrier();
      __builtin_amdgcn_sched_barrier(0);
    }
  };

  const int NS3 = NS - (NS % 3);
#pragma unroll 1
  for (int t0 = 0; t0 < NS3; t0 += 3) {
    body(t0, 0);
    body(t0 + 1, 1);
    body(t0 + 2, 2);
  }
#pragma unroll
  for (int u = 0; u < 3; ++u) {
    const int t = NS3 + u;
    if (t < NS) body(t, u);
  }

  // Epilogue. C/D layout: col = lane&15, row = quad*4 + reg.
#pragma unroll
  for (int mi = 0; mi < 2; ++mi) {
    const int r0 = m0 + wr * 32 + mi * 16 + quad * 4;
#pragma unroll
    for (int ni = 0; ni < 4; ++ni) {
      const int col = n0 + wc * 64 + ni * 16 + l16;
#pragma unroll
      for (int r = 0; r < 4; ++r) {
        const int row = r0 + r;
        const size_t idx = (size_t)row * N + col;
        const float v = acc[mi][ni][r];
        if (MODE == 1) {
          // v = W2[row][col]. B = I/2 + W/6 + W2/24 ->
          // B^T = I/2 - W/6 + W2/24  (W antisymmetric, W2 symmetric).
          O1[idx] = (bf16)v;
          const float w = (float)Wb[idx];
          const float d = (row == col) ? 1.0f : 0.0f;
          O2[idx] = (bf16)(0.5f * d - (1.0f / 6.0f) * w + (1.0f / 24.0f) * v);
        } else {  // MODE 2: Q^T = acc + I + W
          const float w = (float)Wb[idx];
          const float d = (row == col) ? 1.0f : 0.0f;
          O1[idx] = (bf16)(v + d + w);
        }
      }
    }
  }
}

// ---------------------------------------------------------------------------
// G3 kernel (reverted to round-1 version: best measured, 77.3 us, 889 TF).
// C(MxN) f32 = A(MxK) @ Bt(NxK)^T, bf16 in. 256x256 tile, 8 waves (2Mx4N),
// BK=32, 4-deep LDS ring (128 KiB), global_load_lds staging 3 tiles ahead,
// counted vmcnt (never 0 in steady state), one raw s_barrier per K-tile,
// setprio around the MFMA cluster.
// Requires: N == gridDim.x*256 with gridDim.x == 8, K % 128 == 0, K/32 >= 4.
__global__ __launch_bounds__(512, 2) void gemm256(
    const bf16* __restrict__ A, const bf16* __restrict__ Bt,
    float* __restrict__ Cf, int M, int N, int K) {
  __shared__ __align__(16) bf16 As[4 * 256 * 32];   // 64 KB
  __shared__ __align__(16) bf16 Bs[4 * 256 * 32];   // 64 KB

  const int tid  = threadIdx.x;
  const int lane = tid & 63;
  const int wave = tid >> 6;     // 0..7
  const int wr   = wave >> 2;    // 0..1  M-half
  const int wc   = wave & 3;     // 0..3  N-quarter
  const int quad = lane >> 4;
  const int l16  = lane & 15;

  // Bijective XCD swizzle (nwg = 256 divisible by 8).
  const int nwg    = gridDim.x * gridDim.y;
  const int linear = blockIdx.y * gridDim.x + blockIdx.x;
  const int wg = (linear & 7) * (nwg >> 3) + (linear >> 3);
  const int bx = wg & 7;         // gridDim.x == 8 (N == 2048)
  const int by = wg >> 3;
  const int m0 = by * 256;
  const int n0 = bx * 256;

  const int srow  = lane >> 2;
  const int sslot = (lane & 3) ^ ((lane >> 3) & 3);
  const bf16* pA1 = A  + (size_t)(m0 + wave * 16 + srow) * K + sslot * 8;
  const bf16* pA2 = pA1 + (size_t)128 * K;
  const bf16* pB1 = Bt + (size_t)(n0 + wave * 16 + srow) * K + sslot * 8;
  const bf16* pB2 = pB1 + (size_t)128 * K;
  bf16* lA1 = As + wave * 512;          // + buf*8192
  bf16* lA2 = As + wave * 512 + 4096;
  bf16* lB1 = Bs + wave * 512;
  bf16* lB2 = Bs + wave * 512 + 4096;

  const int NT = K >> 5;   // K-tiles of 32

  // Prologue: stage tiles 0,1,2 into ring buffers 0,1,2 (12 loads/thread),
  // then wait for tile 0 only (8 loads stay in flight).
#pragma unroll
  for (int tt = 0; tt < 3; ++tt) {
    gld16(pA1 + tt * 32, lA1 + tt * 8192);
    gld16(pA2 + tt * 32, lA2 + tt * 8192);
    gld16(pB1 + tt * 32, lB1 + tt * 8192);
    gld16(pB2 + tt * 32, lB2 + tt * 8192);
  }
  asm volatile("s_waitcnt vmcnt(8)" ::: "memory");
  __builtin_amdgcn_s_barrier();
  __builtin_amdgcn_sched_barrier(0);

  f32x4 acc[8][4] = {};
  const int rswz = (quad ^ ((l16 >> 1) & 3)) * 8;  // reader swizzle (elems)
  const int arow = wr * 128 + l16;
  const int brow = wc * 64 + l16;

  size_t kpre = 96;   // element k-offset of tile t+3 at t=0

#pragma unroll 1
  for (int t4 = 0; t4 < NT; t4 += 4) {
#pragma unroll
    for (int u = 0; u < 4; ++u) {
      const int t = t4 + u;
      // Issue staging for tile t+3 -> buffer (u+3)&3.
      if (t + 3 < NT) {
        const int b = (u + 3) & 3;
        const size_t ko = kpre + (size_t)u * 32;
        gld16(pA1 + ko, lA1 + b * 8192);
        gld16(pA2 + ko, lA2 + b * 8192);
        gld16(pB1 + ko, lB1 + b * 8192);
        gld16(pB2 + ko, lB2 + b * 8192);
      }
      // Compute tile t from buffer u.
      const bf16* ab = As + u * 8192;
      const bf16* bb = Bs + u * 8192;
      bf16x8 af[8], bfr[4];
#pragma unroll
      for (int mi = 0; mi < 8; ++mi)
        af[mi] = *(const bf16x8*)&ab[(arow + mi * 16) * 32 + rswz];
#pragma unroll
      for (int ni = 0; ni < 4; ++ni)
        bfr[ni] = *(const bf16x8*)&bb[(brow + ni * 16) * 32 + rswz];
      __builtin_amdgcn_s_setprio(1);
#pragma unroll
      for (int mi = 0; mi < 8; ++mi)
#pragma unroll
        for (int ni = 0; ni < 4; ++ni)
          acc[mi][ni] = __builtin_amdgcn_mfma_f32_16x16x32_bf16(
              af[mi], bfr[ni], acc[mi][ni], 0, 0, 0);
      __builtin_amdgcn_s_setprio(0);
      // K-tile boundary: retire tile t+1's 4 loads, keep the rest in flight.
      if (t < NT - 1) {
        if (t < NT - 3)
          asm volatile("s_waitcnt vmcnt(8)" ::: "memory");
        else if (t == NT - 3)
          asm volatile("s_waitcnt vmcnt(4)" ::: "memory");
        else
          asm volatile("s_waitcnt vmcnt(0)" ::: "memory");
        __builtin_amdgcn_sched_barrier(0);
        __builtin_amdgcn_s_barrier();
        __builtin_amdgcn_sched_barrier(0);
      }
    }
    kpre += 128;
  }

  // Epilogue: C/D layout col = lane&15, row = quad*4 + reg.
#pragma unroll
  for (int mi = 0; mi < 8; ++mi) {
    const int r0 = m0 + wr * 128 + mi * 16 + quad * 4;
#pragma unroll
    for (int ni = 0; ni < 4; ++ni) {
      const int col = n0 + wc * 64 + ni * 16 + l16;
#pragma unroll
      for (int r = 0; r < 4; ++r)
        Cf[(size_t)(r0 + r) * N + col] = acc[mi][ni][r];
    }
  }
}

extern "C" void kernel_launch(void* const* d_in, const int* in_sizes, int n_in,
                              void* d_out, int out_size, void* d_ws, size_t ws_size,
                              hipStream_t stream) {
  const float* X     = (const float*)d_in[0];
  const float* Sflat = (const float*)d_in[1];
  float* out = (float*)d_out;
  char* ws = (char*)d_ws;

  // Workspace (72 MB total):
  bf16* Xb   = (bf16*)(ws);                 // 32 MB  bf16(X)
  bf16* Wb   = (bf16*)(ws + (32u << 20));   //  8 MB  bf16(W),   W = -S
  bf16* Wtb  = (bf16*)(ws + (40u << 20));   //  8 MB  bf16(W^T)
  bf16* W2b  = (bf16*)(ws + (48u << 20));   //  8 MB  bf16(W^2)
  bf16* Btm  = (bf16*)(ws + (56u << 20));   //  8 MB  bf16(B^T) operand for G2
  bf16* Qtb  = (bf16*)(ws + (64u << 20));   //  8 MB  bf16(Q^T)

  unfold_kernel<<<(N_DIM * N_DIM) / 256, 256, 0, stream>>>(Sflat, Wb, Wtb);
  cast_kernel<<<(BATCH_SZ * N_DIM / 4) / 256, 256, 0, stream>>>(X, Xb);

  // Weight GEMMs: 64x128 tiles -> 512 blocks = 2 blocks/CU, deep-pipelined.
  const dim3 gW(N_DIM / 128, N_DIM / 64);
  // G1: W2 = W @ W;  epilogue also emits B^T = I/2 - W/6 + W2/24.
  gemm_w<1><<<gW, 256, 0, stream>>>(Wb, Wtb, W2b, Btm, Wb,
                                    N_DIM, N_DIM, N_DIM);
  // G2: Q^T = I + W + W2 @ B   (Bt operand = B^T).
  gemm_w<2><<<gW, 256, 0, stream>>>(W2b, Btm, Qtb, nullptr, Wb,
                                    N_DIM, N_DIM, N_DIM);
  // G3: out = X @ Q  (Bt = Q^T row-major). 256x256 tiles -> 256 blocks,
  // round-1 pipelined ring-buffer kernel (best measured).
  gemm256<<<dim3(N_DIM / 256, BATCH_SZ / 256), 512, 0, stream>>>(
      Xb, Qtb, out, BATCH_SZ, N_DIM, N_DIM);
}